// Round 11
// baseline (433.118 us; speedup 1.0000x reference)
//
#include <hip/hip_runtime.h>
#include <math.h>

#define B_   128
#define R_   1152
#define C_   16
#define RS_  128
#define RCH_ 9             // R_/RS_
#define NB_  256           // blocks (1 per CU, cooperative)
#define NT_  512           // threads per block

// ws float offsets
#define WS_SP   0          // RS_*32768 = 4194304   sp[rs][b][co]
#define WS_V    4194304    // 32768                 v[b][co]
#define WS_BLOG 4227072    // 18432                 blog[r][c]
#define WS_WT   4245504    // 2359296               Wt4[r*512 + d*64 + co4]
#define WS_BAR  6604800    // 2 uints (barrier cnt, gen)

__device__ __forceinline__ float squashf(float s) {
    return s * fabsf(s) / (1.0f + s * s);
}

// Sense-reversal grid barrier. Release: leader's ACQ_REL fetch_add publishes the
// block's prior stores (after __syncthreads drains them to L2; agent scope forces
// L2 writeback). Spin is RELAXED (agent-scope atomic loads read the coherence
// point, no per-poll L2 invalidate); one ACQUIRE load on exit.
__device__ __forceinline__ void grid_bar(unsigned* cnt, unsigned* gen) {
    __syncthreads();
    if (threadIdx.x == 0) {
        const unsigned g = __hip_atomic_load(gen, __ATOMIC_RELAXED, __HIP_MEMORY_SCOPE_AGENT);
        const unsigned a = __hip_atomic_fetch_add(cnt, 1u, __ATOMIC_ACQ_REL, __HIP_MEMORY_SCOPE_AGENT);
        if (a == NB_ - 1) {
            __hip_atomic_store(cnt, 0u, __ATOMIC_RELAXED, __HIP_MEMORY_SCOPE_AGENT);
            __hip_atomic_fetch_add(gen, 1u, __ATOMIC_RELEASE, __HIP_MEMORY_SCOPE_AGENT);
        } else {
            while (__hip_atomic_load(gen, __ATOMIC_RELAXED, __HIP_MEMORY_SCOPE_AGENT) == g)
                __builtin_amdgcn_s_sleep(2);
            (void)__hip_atomic_load(gen, __ATOMIC_ACQUIRE, __HIP_MEMORY_SCOPE_AGENT);
        }
    }
    __syncthreads();
}

__global__ __launch_bounds__(NT_, 1) void caps_k(const float* __restrict__ x,
                                                 const float* __restrict__ W,
                                                 float* __restrict__ out,
                                                 float* __restrict__ ws) {
    const int blk = blockIdx.x;
    const int t   = threadIdx.x;

    float* sp   = ws + WS_SP;
    float* v    = ws + WS_V;
    float* blog = ws + WS_BLOG;
    float* wt   = ws + WS_WT;
    unsigned* cnt = (unsigned*)(ws + WS_BAR);
    unsigned* gen = cnt + 1;

    const float4* __restrict__ X4 = (const float4*)x;
    const float4* __restrict__ W4 = (const float4*)W;
    float4* __restrict__ Wt4 = (float4*)wt;

    __shared__ float4 sh4[1216];        // 19.5 KB phase-shared buffer
    __shared__ float  red[512];
    __shared__ float4 pt4[32];
    __shared__ float  colinv[16];
    __shared__ float  cwl[RCH_ * 16];

    // ---------- P0: build Wt (row-local transpose via LDS pitch-65) ----------
    for (int r = blk; r < R_; r += NB_) {
        sh4[(t & 7) * 65 + (t >> 3)] = W4[r * 512 + t];   // j = co4*8 + d
        __syncthreads();
        Wt4[r * 512 + t] = sh4[(t >> 6) * 65 + (t & 63)]; // [d][co4], coalesced
        __syncthreads();
    }
    grid_bar(cnt, gen);

    for (int it = 0; it < 3; ++it) {
        // ---------------- G: sp[rs][b][co] ----------------
        {
            const int bt = blk >> 7, rs = blk & 127, r0 = rs * RCH_;
            const int co4 = t & 63, b8 = t >> 6, c = co4 >> 2;

            if (it > 0) {   // column softmax prepass (no max-sub; |blog| small)
                const float4* BL4 = (const float4*)blog;
                float4 e4; e4.x = 0.f; e4.y = 0.f; e4.z = 0.f; e4.w = 0.f;
                #pragma unroll
                for (int i = 0; i < 9; ++i) {
                    const float4 bv = BL4[i * 512 + t];
                    e4.x += __expf(bv.x); e4.y += __expf(bv.y);
                    e4.z += __expf(bv.z); e4.w += __expf(bv.w);
                }
                #pragma unroll
                for (int d = 4; d < 64; d <<= 1) {
                    e4.x += __shfl_xor(e4.x, d); e4.y += __shfl_xor(e4.y, d);
                    e4.z += __shfl_xor(e4.z, d); e4.w += __shfl_xor(e4.w, d);
                }
                if ((t & 63) < 4) pt4[(t >> 6) * 4 + (t & 3)] = e4;
                __syncthreads();
                if (t < 4) {
                    float4 s = pt4[t];
                    #pragma unroll
                    for (int w2 = 1; w2 < 8; ++w2) {
                        const float4 q = pt4[w2 * 4 + t];
                        s.x += q.x; s.y += q.y; s.z += q.z; s.w += q.w;
                    }
                    colinv[t * 4 + 0] = 1.0f / s.x; colinv[t * 4 + 1] = 1.0f / s.y;
                    colinv[t * 4 + 2] = 1.0f / s.z; colinv[t * 4 + 3] = 1.0f / s.w;
                }
                __syncthreads();
                if (t < RCH_ * 16) {
                    const int rl = t >> 4, cc = t & 15;
                    cwl[t] = __expf(blog[(r0 + rl) * 16 + cc]) * colinv[cc];
                }
            }

            // stage x[bt*64 .. +63][r0..r0+8][0:8] -> 1152 float4
            {
                int u = t;
                { const int bl = u / 18, rem = u % 18;
                  sh4[u] = X4[((bt * 64 + bl) * R_ + r0) * 2 + rem]; }
                u = t + 512;
                { const int bl = u / 18, rem = u % 18;
                  sh4[u] = X4[((bt * 64 + bl) * R_ + r0) * 2 + rem]; }
                u = t + 1024;
                if (u < 1152) {
                    const int bl = u / 18, rem = u % 18;
                    sh4[u] = X4[((bt * 64 + bl) * R_ + r0) * 2 + rem];
                }
            }
            __syncthreads();

            float acc[8][4];
            #pragma unroll
            for (int j = 0; j < 8; ++j)
                #pragma unroll
                for (int q = 0; q < 4; ++q) acc[j][q] = 0.f;

            #pragma unroll 3
            for (int rr = 0; rr < RCH_; ++rr) {
                const float cwv = (it > 0) ? cwl[rr * 16 + c] : (1.0f / (float)R_);
                const float4* wp = Wt4 + ((size_t)(r0 + rr) << 9) + co4;
                const float4 w0 = wp[  0], w1 = wp[ 64], w2 = wp[128], w3 = wp[192];
                const float4 w4 = wp[256], w5 = wp[320], w6 = wp[384], w7 = wp[448];
                #pragma unroll
                for (int j = 0; j < 8; ++j) {
                    const float4 xa = sh4[(b8 * 8 + j) * 18 + rr * 2];
                    const float4 xb = sh4[(b8 * 8 + j) * 18 + rr * 2 + 1];
                    const float d0 = w0.x*xa.x + w0.y*xa.y + w0.z*xa.z + w0.w*xa.w
                                   + w1.x*xb.x + w1.y*xb.y + w1.z*xb.z + w1.w*xb.w;
                    const float d1 = w2.x*xa.x + w2.y*xa.y + w2.z*xa.z + w2.w*xa.w
                                   + w3.x*xb.x + w3.y*xb.y + w3.z*xb.z + w3.w*xb.w;
                    const float d2 = w4.x*xa.x + w4.y*xa.y + w4.z*xa.z + w4.w*xa.w
                                   + w5.x*xb.x + w5.y*xb.y + w5.z*xb.z + w5.w*xb.w;
                    const float d3 = w6.x*xa.x + w6.y*xa.y + w6.z*xa.z + w6.w*xa.w
                                   + w7.x*xb.x + w7.y*xb.y + w7.z*xb.z + w7.w*xb.w;
                    acc[j][0] = fmaf(cwv, d0, acc[j][0]);
                    acc[j][1] = fmaf(cwv, d1, acc[j][1]);
                    acc[j][2] = fmaf(cwv, d2, acc[j][2]);
                    acc[j][3] = fmaf(cwv, d3, acc[j][3]);
                }
            }

            float4* sp4 = (float4*)sp;
            #pragma unroll
            for (int j = 0; j < 8; ++j) {
                const int b = bt * 64 + b8 * 8 + j;
                float4 o4; o4.x = acc[j][0]; o4.y = acc[j][1];
                o4.z = acc[j][2]; o4.w = acc[j][3];
                sp4[(rs * B_ + b) * 64 + co4] = o4;
            }
        }
        grid_bar(cnt, gen);

        // ---------------- R: v = squash(sum_rs sp) ----------------
        {
            float* vout = (it == 2) ? out : v;
            const int li = t & 127, kq = t >> 7;
            const int idx = blk * 128 + li;
            const float* p = sp + (size_t)kq * 32 * 32768 + idx;
            float a0 = 0.f, a1 = 0.f, a2 = 0.f, a3 = 0.f;
            #pragma unroll 8
            for (int k = 0; k < 32; k += 4) {
                a0 += p[(k + 0) * 32768];
                a1 += p[(k + 1) * 32768];
                a2 += p[(k + 2) * 32768];
                a3 += p[(k + 3) * 32768];
            }
            red[t] = (a0 + a1) + (a2 + a3);
            __syncthreads();
            if (t < 128)
                vout[idx] = squashf((red[t] + red[t + 128]) + (red[t + 256] + red[t + 384]));
        }
        if (it == 2) return;
        grid_bar(cnt, gen);

        // ---------------- A: blog[r,c] (+)= mean_b <u_hat, v> ----------------
        for (int u = blk; u < 288; u += NB_) {
            const int r0a = u * 4;
            const int w = t >> 6, lane = t & 63;
            const int rr = w & 3, half = w >> 2;
            const int co4a = lane, ca = lane >> 2;

            __syncthreads();          // sh4 reuse
            #pragma unroll
            for (int kk = 0; kk < 2; ++kk) {
                const int uu = t + kk * 512;         // 0..1023
                const int b = uu >> 3, rem = uu & 7;
                sh4[uu] = X4[(b * R_ + r0a) * 2 + rem];
            }
            __syncthreads();

            float y[8][4];
            #pragma unroll
            for (int i = 0; i < 8; ++i)
                #pragma unroll
                for (int q = 0; q < 4; ++q) y[i][q] = 0.f;

            const int b0 = half * 64;
            const float4* __restrict__ V4 = (const float4*)v;
            #pragma unroll 4
            for (int bb = 0; bb < 64; ++bb) {
                const int b = b0 + bb;
                const float4 xa = sh4[b * 8 + rr * 2];
                const float4 xb = sh4[b * 8 + rr * 2 + 1];
                const float4 vv = V4[b * 64 + co4a];
                const float xs[8] = {xa.x, xa.y, xa.z, xa.w, xb.x, xb.y, xb.z, xb.w};
                #pragma unroll
                for (int i = 0; i < 8; ++i) {
                    y[i][0] = fmaf(xs[i], vv.x, y[i][0]);
                    y[i][1] = fmaf(xs[i], vv.y, y[i][1]);
                    y[i][2] = fmaf(xs[i], vv.z, y[i][2]);
                    y[i][3] = fmaf(xs[i], vv.w, y[i][3]);
                }
            }

            const float4* wp = Wt4 + ((size_t)(r0a + rr) << 9) + co4a;
            float part = 0.f;
            #pragma unroll
            for (int q = 0; q < 4; ++q) {
                const float4 w0 = wp[(2 * q) * 64];
                const float4 w1 = wp[(2 * q + 1) * 64];
                part += w0.x*y[0][q] + w0.y*y[1][q] + w0.z*y[2][q] + w0.w*y[3][q]
                      + w1.x*y[4][q] + w1.y*y[5][q] + w1.z*y[6][q] + w1.w*y[7][q];
            }
            part += __shfl_xor(part, 1);
            part += __shfl_xor(part, 2);
            if ((lane & 3) == 0) red[w * 16 + ca] = part;
            __syncthreads();
            if (t < 64) {
                const int rr2 = t >> 4, cc = t & 15;
                const float val = (red[rr2 * 16 + cc] + red[(rr2 + 4) * 16 + cc])
                                  * (1.0f / (float)B_);
                const int idx = (r0a + rr2) * 16 + cc;
                blog[idx] = (it == 0) ? val : (blog[idx] + val);
            }
        }
        grid_bar(cnt, gen);
    }
}

extern "C" void kernel_launch(void* const* d_in, const int* in_sizes, int n_in,
                              void* d_out, int out_size, void* d_ws, size_t ws_size,
                              hipStream_t stream) {
    const float* x = (const float*)d_in[0];   // [128,1152,8]
    const float* W = (const float*)d_in[1];   // [1,1152,16,16,8]
    float* out = (float*)d_out;               // [128,16,16]
    float* ws  = (float*)d_ws;                // ~26.4 MB used

    hipMemsetAsync(ws + WS_BAR, 0, 2 * sizeof(unsigned), stream);

    void* args[] = { (void*)&x, (void*)&W, (void*)&out, (void*)&ws };
    hipLaunchCooperativeKernel((void*)caps_k, dim3(NB_), dim3(NT_), args, 0, stream);
}

// Round 12
// 197.030 us; speedup vs baseline: 2.1982x; 2.1982x over previous
//
#include <hip/hip_runtime.h>
#include <math.h>

#define B_   128
#define R_   1152
#define C_   16
#define O_   16
#define RS_  64
#define RCH_ 18            // R_/RS_

// ws float offsets
#define WS_SP   0          // RS_*32768 = 2097152
#define WS_V    2097152    // 32768
#define WS_BLOG 2129920    // 18432
#define WS_WT   2148352    // 2359296 (Wt4[r*512 + d*64 + co4])

__device__ __forceinline__ float squashf(float s) {
    return s * fabsf(s) / (1.0f + s * s);
}

// ---------- G1 (iter 0, cw = 1/R): W via 6-r pitch-65 LDS windows; bt==0 writes Wt.
__global__ __launch_bounds__(256) void gemm_s_first_k(const float* __restrict__ x,
                                                      const float* __restrict__ W,
                                                      float* __restrict__ wt,
                                                      float* __restrict__ sp) {
    const int bt  = blockIdx.x;
    const int rs  = blockIdx.y;
    const int t   = threadIdx.x;
    const int co4 = t & 63;
    const int b4  = t >> 6;
    const int r0  = rs * RCH_;

    __shared__ float4 wl4[6 * 520];     // 48.75 KB, one 6-r window
    __shared__ float4 xl4[576];         // 16 b x 18 r x 2 f4 = 9 KB

    const float4* __restrict__ X4 = (const float4*)x;
    const float4* __restrict__ W4 = (const float4*)W;
    float4* __restrict__ Wt4 = (float4*)wt;

    // stage x tile (full 18-r chunk)
    #pragma unroll
    for (int k = 0; k < 3; ++k) {
        const int u = t + k * 256;
        if (u < 576) {
            const int bl = u / 36, rem = u % 36;
            xl4[u] = X4[((bt * 16 + bl) * R_ + r0) * 2 + rem];
        }
    }

    float acc[4][4];
    #pragma unroll
    for (int j = 0; j < 4; ++j)
        #pragma unroll
        for (int q = 0; q < 4; ++q) acc[j][q] = 0.f;

    for (int wdw = 0; wdw < 3; ++wdw) {
        const int rw0 = wdw * 6;
        __syncthreads();                 // prev-window reads done / x staged
        #pragma unroll
        for (int kk = 0; kk < 12; ++kk) {
            const int u  = t + kk * 256;        // 0..3071
            const int rr = u >> 9, j = u & 511; // j = co4*8 + d
            const float4 wv = W4[(r0 + rw0) * 512 + u];
            wl4[rr * 520 + (j & 7) * 65 + (j >> 3)] = wv;
            if (bt == 0)
                Wt4[(size_t)(r0 + rw0 + rr) * 512 + (j & 7) * 64 + (j >> 3)] = wv;
        }
        __syncthreads();

        #pragma unroll
        for (int rr = 0; rr < 6; ++rr) {
            const int rrg = rw0 + rr;
            const int wb = rr * 520 + co4;
            const float4 w0 = wl4[wb +   0], w1 = wl4[wb +  65];
            const float4 w2 = wl4[wb + 130], w3 = wl4[wb + 195];
            const float4 w4 = wl4[wb + 260], w5 = wl4[wb + 325];
            const float4 w6 = wl4[wb + 390], w7 = wl4[wb + 455];
            #pragma unroll
            for (int j = 0; j < 4; ++j) {
                const float4 xa = xl4[(b4 * 4 + j) * 36 + rrg * 2];
                const float4 xb = xl4[(b4 * 4 + j) * 36 + rrg * 2 + 1];
                const float d0 = w0.x*xa.x + w0.y*xa.y + w0.z*xa.z + w0.w*xa.w
                               + w1.x*xb.x + w1.y*xb.y + w1.z*xb.z + w1.w*xb.w;
                const float d1 = w2.x*xa.x + w2.y*xa.y + w2.z*xa.z + w2.w*xa.w
                               + w3.x*xb.x + w3.y*xb.y + w3.z*xb.z + w3.w*xb.w;
                const float d2 = w4.x*xa.x + w4.y*xa.y + w4.z*xa.z + w4.w*xa.w
                               + w5.x*xb.x + w5.y*xb.y + w5.z*xb.z + w5.w*xb.w;
                const float d3 = w6.x*xa.x + w6.y*xa.y + w6.z*xa.z + w6.w*xa.w
                               + w7.x*xb.x + w7.y*xb.y + w7.z*xb.z + w7.w*xb.w;
                const float cwv = 1.0f / (float)R_;
                acc[j][0] = fmaf(cwv, d0, acc[j][0]);
                acc[j][1] = fmaf(cwv, d1, acc[j][1]);
                acc[j][2] = fmaf(cwv, d2, acc[j][2]);
                acc[j][3] = fmaf(cwv, d3, acc[j][3]);
            }
        }
    }

    float4* sp4 = (float4*)sp;
    #pragma unroll
    for (int j = 0; j < 4; ++j) {
        const int b = bt * 16 + b4 * 4 + j;
        float4 o4; o4.x = acc[j][0]; o4.y = acc[j][1]; o4.z = acc[j][2]; o4.w = acc[j][3];
        sp4[(rs * B_ + b) * 64 + co4] = o4;
    }
}

// ---------- G (iters 1,2): W fragments streamed coalesced from Wt; softmax prepass. ----
__global__ __launch_bounds__(256) void gemm_s_k(const float* __restrict__ x,
                                                const float* __restrict__ wt,
                                                const float* __restrict__ blog,
                                                float* __restrict__ sp) {
    const int bt  = blockIdx.x;
    const int rs  = blockIdx.y;
    const int t   = threadIdx.x;
    const int co4 = t & 63;
    const int b4  = t >> 6;
    const int c   = co4 >> 2;
    const int r0  = rs * RCH_;

    __shared__ float4 xl4[576];
    __shared__ float4 part[16];
    __shared__ float  colinv[16];
    __shared__ float  cwl[RCH_ * 16];   // 288

    const float4* __restrict__ X4  = (const float4*)x;
    const float4* __restrict__ Wt4 = (const float4*)wt;

    // stage x tile
    #pragma unroll
    for (int k = 0; k < 3; ++k) {
        const int u = t + k * 256;
        if (u < 576) {
            const int bl = u / 36, rem = u % 36;
            xl4[u] = X4[((bt * 16 + bl) * R_ + r0) * 2 + rem];
        }
    }

    // prepass: colinv[c] = 1 / sum_r exp(blog[r,c])
    {
        const float4* BL4 = (const float4*)blog;
        const int g = t & 3;
        float4 e4; e4.x = 0.f; e4.y = 0.f; e4.z = 0.f; e4.w = 0.f;
        #pragma unroll
        for (int i = 0; i < 18; ++i) {
            const float4 bv = BL4[i * 256 + t];
            e4.x += __expf(bv.x); e4.y += __expf(bv.y);
            e4.z += __expf(bv.z); e4.w += __expf(bv.w);
        }
        #pragma unroll
        for (int d = 4; d < 64; d <<= 1) {
            e4.x += __shfl_xor(e4.x, d); e4.y += __shfl_xor(e4.y, d);
            e4.z += __shfl_xor(e4.z, d); e4.w += __shfl_xor(e4.w, d);
        }
        if ((t & 63) < 4) part[(t >> 6) * 4 + g] = e4;
        __syncthreads();
        if (t < 4) {
            const float4 a = part[t], b = part[4 + t], cc4 = part[8 + t], d = part[12 + t];
            colinv[t * 4 + 0] = 1.0f / ((a.x + b.x) + (cc4.x + d.x));
            colinv[t * 4 + 1] = 1.0f / ((a.y + b.y) + (cc4.y + d.y));
            colinv[t * 4 + 2] = 1.0f / ((a.z + b.z) + (cc4.z + d.z));
            colinv[t * 4 + 3] = 1.0f / ((a.w + b.w) + (cc4.w + d.w));
        }
        __syncthreads();
        for (int u2 = t; u2 < RCH_ * 16; u2 += 256) {
            const int rl = u2 >> 4, cc = u2 & 15;
            cwl[u2] = __expf(blog[(r0 + rl) * 16 + cc]) * colinv[cc];
        }
    }
    __syncthreads();

    float acc[4][4];
    #pragma unroll
    for (int j = 0; j < 4; ++j)
        #pragma unroll
        for (int q = 0; q < 4; ++q) acc[j][q] = 0.f;

    #pragma unroll 3
    for (int rr = 0; rr < RCH_; ++rr) {
        const float cwv = cwl[rr * 16 + c];
        const float4* wp = Wt4 + ((size_t)(r0 + rr) << 9) + co4;   // lane-stride 16B
        const float4 w0 = wp[  0], w1 = wp[ 64], w2 = wp[128], w3 = wp[192];
        const float4 w4 = wp[256], w5 = wp[320], w6 = wp[384], w7 = wp[448];
        #pragma unroll
        for (int j = 0; j < 4; ++j) {
            const float4 xa = xl4[(b4 * 4 + j) * 36 + rr * 2];
            const float4 xb = xl4[(b4 * 4 + j) * 36 + rr * 2 + 1];
            const float d0 = w0.x*xa.x + w0.y*xa.y + w0.z*xa.z + w0.w*xa.w
                           + w1.x*xb.x + w1.y*xb.y + w1.z*xb.z + w1.w*xb.w;
            const float d1 = w2.x*xa.x + w2.y*xa.y + w2.z*xa.z + w2.w*xa.w
                           + w3.x*xb.x + w3.y*xb.y + w3.z*xb.z + w3.w*xb.w;
            const float d2 = w4.x*xa.x + w4.y*xa.y + w4.z*xa.z + w4.w*xa.w
                           + w5.x*xb.x + w5.y*xb.y + w5.z*xb.z + w5.w*xb.w;
            const float d3 = w6.x*xa.x + w6.y*xa.y + w6.z*xa.z + w6.w*xa.w
                           + w7.x*xb.x + w7.y*xb.y + w7.z*xb.z + w7.w*xb.w;
            acc[j][0] = fmaf(cwv, d0, acc[j][0]);
            acc[j][1] = fmaf(cwv, d1, acc[j][1]);
            acc[j][2] = fmaf(cwv, d2, acc[j][2]);
            acc[j][3] = fmaf(cwv, d3, acc[j][3]);
        }
    }

    float4* sp4 = (float4*)sp;
    #pragma unroll
    for (int j = 0; j < 4; ++j) {
        const int b = bt * 16 + b4 * 4 + j;
        float4 o4; o4.x = acc[j][0]; o4.y = acc[j][1]; o4.z = acc[j][2]; o4.w = acc[j][3];
        sp4[(rs * B_ + b) * 64 + co4] = o4;
    }
}

// ---------- R: v[b,co] = squash(sum_k sp[k][b][co]); grid 256 x 512, k-split x4 ----
__global__ __launch_bounds__(512) void reduce_squash_k(const float* __restrict__ sp,
                                                       float* __restrict__ outv) {
    const int t   = threadIdx.x;
    const int li  = t & 127;
    const int kq  = t >> 7;               // 0..3 (16 slices each)
    const int idx = blockIdx.x * 128 + li;
    const float* p = sp + (size_t)kq * 16 * 32768 + idx;
    float a0 = 0.f, a1 = 0.f, a2 = 0.f, a3 = 0.f;
    #pragma unroll
    for (int k = 0; k < 16; k += 4) {
        a0 += p[(k + 0) * 32768];
        a1 += p[(k + 1) * 32768];
        a2 += p[(k + 2) * 32768];
        a3 += p[(k + 3) * 32768];
    }
    __shared__ float red[512];
    red[t] = (a0 + a1) + (a2 + a3);
    __syncthreads();
    if (t < 128) {
        const float s = (red[t] + red[t + 128]) + (red[t + 256] + red[t + 384]);
        outv[idx] = squashf(s);
    }
}

// ---------- A: blog[r,c] (+)= (1/B) sum_{b,o} u_hat[b,r,co]*v[b,co] ----------
// grid 288 x 512 (8 waves: rr = w&3, half = w>>2). W from Wt (coalesced global).
template <bool FIRST>
__global__ __launch_bounds__(512) void a_k(const float* __restrict__ x,
                                           const float* __restrict__ wt,
                                           const float* __restrict__ v,
                                           float* __restrict__ blog) {
    const int r0 = blockIdx.x * 4;
    const int t  = threadIdx.x;
    const int w  = t >> 6, lane = t & 63;
    const int rr = w & 3, half = w >> 2;
    const int co4 = lane, c = lane >> 2;

    __shared__ float4 xl[128 * 8];        // 16 KB
    __shared__ float  red[128];
    const float4* __restrict__ X4  = (const float4*)x;
    const float4* __restrict__ V4  = (const float4*)v;
    const float4* __restrict__ Wt4 = (const float4*)wt;

    #pragma unroll
    for (int kk = 0; kk < 2; ++kk) {
        const int u = t + kk * 512;       // 0..1023
        const int b = u >> 3, rem = u & 7;
        xl[u] = X4[(b * R_ + r0) * 2 + rem];
    }
    __syncthreads();

    float y[8][4];
    #pragma unroll
    for (int i = 0; i < 8; ++i)
        #pragma unroll
        for (int q = 0; q < 4; ++q) y[i][q] = 0.f;

    const int b0 = half * 64;
    #pragma unroll 4
    for (int bb = 0; bb < 64; ++bb) {
        const int b = b0 + bb;
        const float4 xa = xl[b * 8 + rr * 2];
        const float4 xb = xl[b * 8 + rr * 2 + 1];
        const float4 vv = V4[b * 64 + co4];
        const float xs[8] = {xa.x, xa.y, xa.z, xa.w, xb.x, xb.y, xb.z, xb.w};
        #pragma unroll
        for (int i = 0; i < 8; ++i) {
            y[i][0] = fmaf(xs[i], vv.x, y[i][0]);
            y[i][1] = fmaf(xs[i], vv.y, y[i][1]);
            y[i][2] = fmaf(xs[i], vv.z, y[i][2]);
            y[i][3] = fmaf(xs[i], vv.w, y[i][3]);
        }
    }

    const float4* wp = Wt4 + ((size_t)(r0 + rr) << 9) + co4;
    float part = 0.f;
    #pragma unroll
    for (int q = 0; q < 4; ++q) {
        const float4 w0 = wp[(2 * q) * 64];
        const float4 w1 = wp[(2 * q + 1) * 64];
        part += w0.x*y[0][q] + w0.y*y[1][q] + w0.z*y[2][q] + w0.w*y[3][q]
              + w1.x*y[4][q] + w1.y*y[5][q] + w1.z*y[6][q] + w1.w*y[7][q];
    }
    part += __shfl_xor(part, 1);
    part += __shfl_xor(part, 2);
    if ((lane & 3) == 0) red[w * 16 + c] = part;
    __syncthreads();
    if (t < 64) {
        const int rr2 = t >> 4, cc = t & 15;
        const float val = (red[rr2 * 16 + cc] + red[(rr2 + 4) * 16 + cc]) * (1.0f / (float)B_);
        const int idx = (r0 + rr2) * 16 + cc;
        blog[idx] = FIRST ? val : (blog[idx] + val);
    }
}

extern "C" void kernel_launch(void* const* d_in, const int* in_sizes, int n_in,
                              void* d_out, int out_size, void* d_ws, size_t ws_size,
                              hipStream_t stream) {
    const float* x = (const float*)d_in[0];   // [128,1152,8]
    const float* W = (const float*)d_in[1];   // [1,1152,16,16,8]
    float* out = (float*)d_out;               // [128,16,16]
    float* ws  = (float*)d_ws;                // ~18 MB used

    float* sp   = ws + WS_SP;
    float* v    = ws + WS_V;
    float* blog = ws + WS_BLOG;
    float* wt   = ws + WS_WT;

    // iter 0 (softmax(0) == 1/R exactly; also builds Wt)
    gemm_s_first_k<<<dim3(8, RS_), 256, 0, stream>>>(x, W, wt, sp);
    reduce_squash_k<<<256, 512, 0, stream>>>(sp, v);
    a_k<true><<<288, 512, 0, stream>>>(x, wt, v, blog);

    // iter 1
    gemm_s_k<<<dim3(8, RS_), 256, 0, stream>>>(x, wt, blog, sp);
    reduce_squash_k<<<256, 512, 0, stream>>>(sp, v);
    a_k<false><<<288, 512, 0, stream>>>(x, wt, v, blog);

    // iter 2
    gemm_s_k<<<dim3(8, RS_), 256, 0, stream>>>(x, wt, blog, sp);
    reduce_squash_k<<<256, 512, 0, stream>>>(sp, out);
}

// Round 13
// 181.150 us; speedup vs baseline: 2.3909x; 1.0877x over previous
//
#include <hip/hip_runtime.h>
#include <math.h>

#define B_   128
#define R_   1152
#define C_   16
#define O_   16
#define RS_  64
#define RCH_ 18            // R_/RS_

// ws float offsets
#define WS_SP   0          // RS_*32768 = 2097152
#define WS_V    2097152    // 32768
#define WS_BLOG 2129920    // 18432
#define WS_WT   2148352    // 2359296 (Wt4[r*512 + d*64 + co4])

__device__ __forceinline__ float squashf(float s) {
    return s * fabsf(s) / (1.0f + s * s);
}

// ---------- T: Wt4[r*512 + d*64 + co4] = W4[r*512 + co4*8 + d]  (pitch-65 LDS swizzle)
__global__ __launch_bounds__(512) void wtrans_k(const float* __restrict__ W,
                                                float* __restrict__ wt) {
    const int r = blockIdx.x;
    const int t = threadIdx.x;
    __shared__ float4 sh[520];
    const float4* __restrict__ W4 = (const float4*)W;
    float4* __restrict__ Wt4 = (float4*)wt;

    sh[(t & 7) * 65 + (t >> 3)] = W4[r * 512 + t];     // t = co4*8 + d
    __syncthreads();
    Wt4[r * 512 + t] = sh[(t >> 6) * 65 + (t & 63)];   // t = d*64 + co4
}

// ---------- G: sp[rs][b][co] = sum_{r in chunk,i} x[b,r,i]*cw[r,c]*W[r,co,i]
// grid (8 bt, RS_ rs) x 256. W fragments streamed coalesced from Wt.
// FIRST: cw = 1/R exactly (iter 0), no prepass. Else: column softmax prepass.
template <bool FIRST>
__global__ __launch_bounds__(256) void gemm_s_k(const float* __restrict__ x,
                                                const float* __restrict__ wt,
                                                const float* __restrict__ blog,
                                                float* __restrict__ sp) {
    const int bt  = blockIdx.x;
    const int rs  = blockIdx.y;
    const int t   = threadIdx.x;
    const int co4 = t & 63;
    const int b4  = t >> 6;
    const int c   = co4 >> 2;
    const int r0  = rs * RCH_;

    __shared__ float4 xl4[576];         // 16 b x 18 r x 2 f4 = 9 KB
    __shared__ float4 part[16];
    __shared__ float  colinv[16];
    __shared__ float  cwl[RCH_ * 16];   // 288

    const float4* __restrict__ X4  = (const float4*)x;
    const float4* __restrict__ Wt4 = (const float4*)wt;

    // stage x tile
    #pragma unroll
    for (int k = 0; k < 3; ++k) {
        const int u = t + k * 256;
        if (u < 576) {
            const int bl = u / 36, rem = u % 36;
            xl4[u] = X4[((bt * 16 + bl) * R_ + r0) * 2 + rem];
        }
    }

    // prepass: colinv[c] = 1 / sum_r exp(blog[r,c]); cwl = softmax rows (skip on iter 0)
    if (!FIRST) {
        const float4* BL4 = (const float4*)blog;
        const int g = t & 3;
        float4 e4; e4.x = 0.f; e4.y = 0.f; e4.z = 0.f; e4.w = 0.f;
        #pragma unroll
        for (int i = 0; i < 18; ++i) {
            const float4 bv = BL4[i * 256 + t];
            e4.x += __expf(bv.x); e4.y += __expf(bv.y);
            e4.z += __expf(bv.z); e4.w += __expf(bv.w);
        }
        #pragma unroll
        for (int d = 4; d < 64; d <<= 1) {
            e4.x += __shfl_xor(e4.x, d); e4.y += __shfl_xor(e4.y, d);
            e4.z += __shfl_xor(e4.z, d); e4.w += __shfl_xor(e4.w, d);
        }
        if ((t & 63) < 4) part[(t >> 6) * 4 + g] = e4;
        __syncthreads();
        if (t < 4) {
            const float4 a = part[t], b = part[4 + t], cc4 = part[8 + t], d = part[12 + t];
            colinv[t * 4 + 0] = 1.0f / ((a.x + b.x) + (cc4.x + d.x));
            colinv[t * 4 + 1] = 1.0f / ((a.y + b.y) + (cc4.y + d.y));
            colinv[t * 4 + 2] = 1.0f / ((a.z + b.z) + (cc4.z + d.z));
            colinv[t * 4 + 3] = 1.0f / ((a.w + b.w) + (cc4.w + d.w));
        }
        __syncthreads();
        for (int u2 = t; u2 < RCH_ * 16; u2 += 256) {
            const int rl = u2 >> 4, cc = u2 & 15;
            cwl[u2] = __expf(blog[(r0 + rl) * 16 + cc]) * colinv[cc];
        }
    }
    __syncthreads();

    float acc[4][4];
    #pragma unroll
    for (int j = 0; j < 4; ++j)
        #pragma unroll
        for (int q = 0; q < 4; ++q) acc[j][q] = 0.f;

    #pragma unroll 3
    for (int rr = 0; rr < RCH_; ++rr) {
        const float cwv = FIRST ? (1.0f / (float)R_) : cwl[rr * 16 + c];
        const float4* wp = Wt4 + ((size_t)(r0 + rr) << 9) + co4;   // lane-stride 16B
        const float4 w0 = wp[  0], w1 = wp[ 64], w2 = wp[128], w3 = wp[192];
        const float4 w4 = wp[256], w5 = wp[320], w6 = wp[384], w7 = wp[448];
        #pragma unroll
        for (int j = 0; j < 4; ++j) {
            const float4 xa = xl4[(b4 * 4 + j) * 36 + rr * 2];
            const float4 xb = xl4[(b4 * 4 + j) * 36 + rr * 2 + 1];
            const float d0 = w0.x*xa.x + w0.y*xa.y + w0.z*xa.z + w0.w*xa.w
                           + w1.x*xb.x + w1.y*xb.y + w1.z*xb.z + w1.w*xb.w;
            const float d1 = w2.x*xa.x + w2.y*xa.y + w2.z*xa.z + w2.w*xa.w
                           + w3.x*xb.x + w3.y*xb.y + w3.z*xb.z + w3.w*xb.w;
            const float d2 = w4.x*xa.x + w4.y*xa.y + w4.z*xa.z + w4.w*xa.w
                           + w5.x*xb.x + w5.y*xb.y + w5.z*xb.z + w5.w*xb.w;
            const float d3 = w6.x*xa.x + w6.y*xa.y + w6.z*xa.z + w6.w*xa.w
                           + w7.x*xb.x + w7.y*xb.y + w7.z*xb.z + w7.w*xb.w;
            acc[j][0] = fmaf(cwv, d0, acc[j][0]);
            acc[j][1] = fmaf(cwv, d1, acc[j][1]);
            acc[j][2] = fmaf(cwv, d2, acc[j][2]);
            acc[j][3] = fmaf(cwv, d3, acc[j][3]);
        }
    }

    float4* sp4 = (float4*)sp;
    #pragma unroll
    for (int j = 0; j < 4; ++j) {
        const int b = bt * 16 + b4 * 4 + j;
        float4 o4; o4.x = acc[j][0]; o4.y = acc[j][1]; o4.z = acc[j][2]; o4.w = acc[j][3];
        sp4[(rs * B_ + b) * 64 + co4] = o4;
    }
}

// ---------- R: v[b,co] = squash(sum_k sp[k][b][co]); grid 256 x 512, k-split x4 ----
__global__ __launch_bounds__(512) void reduce_squash_k(const float* __restrict__ sp,
                                                       float* __restrict__ outv) {
    const int t   = threadIdx.x;
    const int li  = t & 127;
    const int kq  = t >> 7;               // 0..3 (16 slices each)
    const int idx = blockIdx.x * 128 + li;
    const float* p = sp + (size_t)kq * 16 * 32768 + idx;
    float a0 = 0.f, a1 = 0.f, a2 = 0.f, a3 = 0.f;
    #pragma unroll
    for (int k = 0; k < 16; k += 4) {
        a0 += p[(k + 0) * 32768];
        a1 += p[(k + 1) * 32768];
        a2 += p[(k + 2) * 32768];
        a3 += p[(k + 3) * 32768];
    }
    __shared__ float red[512];
    red[t] = (a0 + a1) + (a2 + a3);
    __syncthreads();
    if (t < 128) {
        const float s = (red[t] + red[t + 128]) + (red[t + 256] + red[t + 384]);
        outv[idx] = squashf(s);
    }
}

// ---------- A: blog[r,c] (+)= (1/B) sum_{b,o} u_hat[b,r,co]*v[b,co] ----------
// grid 288 x 512 (8 waves: rr = w&3, half = w>>2). W from Wt (coalesced global).
template <bool FIRST>
__global__ __launch_bounds__(512) void a_k(const float* __restrict__ x,
                                           const float* __restrict__ wt,
                                           const float* __restrict__ v,
                                           float* __restrict__ blog) {
    const int r0 = blockIdx.x * 4;
    const int t  = threadIdx.x;
    const int w  = t >> 6, lane = t & 63;
    const int rr = w & 3, half = w >> 2;
    const int co4 = lane, c = lane >> 2;

    __shared__ float4 xl[128 * 8];        // 16 KB
    __shared__ float  red[128];
    const float4* __restrict__ X4  = (const float4*)x;
    const float4* __restrict__ V4  = (const float4*)v;
    const float4* __restrict__ Wt4 = (const float4*)wt;

    #pragma unroll
    for (int kk = 0; kk < 2; ++kk) {
        const int u = t + kk * 512;       // 0..1023
        const int b = u >> 3, rem = u & 7;
        xl[u] = X4[(b * R_ + r0) * 2 + rem];
    }
    __syncthreads();

    float y[8][4];
    #pragma unroll
    for (int i = 0; i < 8; ++i)
        #pragma unroll
        for (int q = 0; q < 4; ++q) y[i][q] = 0.f;

    const int b0 = half * 64;
    #pragma unroll 4
    for (int bb = 0; bb < 64; ++bb) {
        const int b = b0 + bb;
        const float4 xa = xl[b * 8 + rr * 2];
        const float4 xb = xl[b * 8 + rr * 2 + 1];
        const float4 vv = V4[b * 64 + co4];
        const float xs[8] = {xa.x, xa.y, xa.z, xa.w, xb.x, xb.y, xb.z, xb.w};
        #pragma unroll
        for (int i = 0; i < 8; ++i) {
            y[i][0] = fmaf(xs[i], vv.x, y[i][0]);
            y[i][1] = fmaf(xs[i], vv.y, y[i][1]);
            y[i][2] = fmaf(xs[i], vv.z, y[i][2]);
            y[i][3] = fmaf(xs[i], vv.w, y[i][3]);
        }
    }

    const float4* wp = Wt4 + ((size_t)(r0 + rr) << 9) + co4;
    float part = 0.f;
    #pragma unroll
    for (int q = 0; q < 4; ++q) {
        const float4 w0 = wp[(2 * q) * 64];
        const float4 w1 = wp[(2 * q + 1) * 64];
        part += w0.x*y[0][q] + w0.y*y[1][q] + w0.z*y[2][q] + w0.w*y[3][q]
              + w1.x*y[4][q] + w1.y*y[5][q] + w1.z*y[6][q] + w1.w*y[7][q];
    }
    part += __shfl_xor(part, 1);
    part += __shfl_xor(part, 2);
    if ((lane & 3) == 0) red[w * 16 + c] = part;
    __syncthreads();
    if (t < 64) {
        const int rr2 = t >> 4, cc = t & 15;
        const float val = (red[rr2 * 16 + cc] + red[(rr2 + 4) * 16 + cc]) * (1.0f / (float)B_);
        const int idx = (r0 + rr2) * 16 + cc;
        blog[idx] = FIRST ? val : (blog[idx] + val);
    }
}

extern "C" void kernel_launch(void* const* d_in, const int* in_sizes, int n_in,
                              void* d_out, int out_size, void* d_ws, size_t ws_size,
                              hipStream_t stream) {
    const float* x = (const float*)d_in[0];   // [128,1152,8]
    const float* W = (const float*)d_in[1];   // [1,1152,16,16,8]
    float* out = (float*)d_out;               // [128,16,16]
    float* ws  = (float*)d_ws;                // ~18 MB used

    float* sp   = ws + WS_SP;
    float* v    = ws + WS_V;
    float* blog = ws + WS_BLOG;
    float* wt   = ws + WS_WT;

    // build Wt once (coalesced transpose)
    wtrans_k<<<R_, 512, 0, stream>>>(W, wt);

    // iter 0 (softmax(0) == 1/R exactly)
    gemm_s_k<true><<<dim3(8, RS_), 256, 0, stream>>>(x, wt, blog, sp);
    reduce_squash_k<<<256, 512, 0, stream>>>(sp, v);
    a_k<true><<<288, 512, 0, stream>>>(x, wt, v, blog);

    // iter 1
    gemm_s_k<false><<<dim3(8, RS_), 256, 0, stream>>>(x, wt, blog, sp);
    reduce_squash_k<<<256, 512, 0, stream>>>(sp, v);
    a_k<false><<<288, 512, 0, stream>>>(x, wt, v, blog);

    // iter 2
    gemm_s_k<false><<<dim3(8, RS_), 256, 0, stream>>>(x, wt, blog, sp);
    reduce_squash_k<<<256, 512, 0, stream>>>(sp, out);
}